// Round 2
// baseline (1310.408 us; speedup 1.0000x reference)
//
#include <hip/hip_runtime.h>
#include <hip/hip_bf16.h>

#define HH 192
#define WW 192
#define HW 36864
#define CC 256
#define OO 256

typedef short bh8 __attribute__((ext_vector_type(8)));
typedef float f32x4 __attribute__((ext_vector_type(4)));

static __device__ __forceinline__ unsigned short f2bf(float f) {
  __hip_bfloat16 h = __float2bfloat16(f);
  return __builtin_bit_cast(unsigned short, h);
}

// ---------------- kernel 0: weight -> bf16, [t][o][c] rows pre-XOR-swizzled ----------------
// wt_sw byte layout: (t*256 + o)*512 + ((c*2) ^ ((o&7)<<4))   (XOR stays within 128B quarter)
__global__ __launch_bounds__(256) void wt_transform(const float* __restrict__ weight,
                                                    unsigned short* __restrict__ wt_sw) {
  int idx = blockIdx.x * 256 + threadIdx.x;   // 65536 = 256 o x 256 c
  int o = idx >> 8, c = idx & 255;
  const float* wp = weight + (size_t)(o * 2304 + c * 9);  // weight[o][c][t]
  int swz = (o & 7) << 4;
  char* base = (char*)wt_sw;
#pragma unroll
  for (int t = 0; t < 9; ++t) {
    unsigned short v = f2bf(wp[t]);
    *(unsigned short*)(base + (size_t)((t * 256 + o) * 512) + ((c * 2) ^ swz)) = v;
  }
}

// ---------------- kernel 1: scale predictor conv -> sx, sy ----------------
__global__ __launch_bounds__(256) void scale_pred(const float* __restrict__ x,
                                                  const float* __restrict__ sp_w,
                                                  const float* __restrict__ sp_b,
                                                  float* __restrict__ sxw,
                                                  float* __restrict__ syw) {
  __shared__ float spw[4608];
  __shared__ float xs[2592];   // 8 ch x 18 x 18
  int bid = blockIdx.x;
  int b = bid / 144; int rem = bid - b * 144;
  int ty0 = (rem / 12) * 16, tx0 = (rem % 12) * 16;
  int tid = threadIdx.x;
  int py = tid >> 4, px = tid & 15;
  for (int i = tid; i < 4608; i += 256) spw[i] = sp_w[i];
  float sp0 = 0.f, sp1 = 0.f;
  for (int cc = 0; cc < 32; ++cc) {
    __syncthreads();
    for (int i = tid; i < 2592; i += 256) {
      int ci = i / 324; int r2 = i - ci * 324; int ry = r2 / 18; int rx = r2 - ry * 18;
      int gy = ty0 - 1 + ry, gx = tx0 - 1 + rx;
      float v = 0.f;
      if ((unsigned)gy < 192u && (unsigned)gx < 192u)
        v = x[((size_t)(b * 256 + cc * 8 + ci) * 192 + gy) * 192 + gx];
      xs[i] = v;
    }
    __syncthreads();
#pragma unroll
    for (int ci = 0; ci < 8; ++ci) {
      int c = cc * 8 + ci;
      const float* wp0 = &spw[c * 9];
      const float* wp1 = &spw[2304 + c * 9];
      const float* xr = &xs[ci * 324 + py * 18 + px];
#pragma unroll
      for (int ky = 0; ky < 3; ++ky) {
#pragma unroll
        for (int kx = 0; kx < 3; ++kx) {
          float v = xr[ky * 18 + kx];
          sp0 = fmaf(v, wp0[ky * 3 + kx], sp0);
          sp1 = fmaf(v, wp1[ky * 3 + kx], sp1);
        }
      }
    }
  }
  sp0 += sp_b[0]; sp1 += sp_b[1];
  int p = b * HW + (ty0 + py) * 192 + tx0 + px;
  sxw[p] = __expf(fminf(fmaxf(sp0, -2.f), 2.f));
  syw[p] = __expf(fminf(fmaxf(sp1, -2.f), 2.f));
}

// ---------------- kernel 2: main deformable-conv GEMM ----------------
// Block: 64 pixels (one x-strip of row y) x 256 o.  4 waves, wave w owns o-range [w*64, w*64+64).
// MFMA 16x16x32 bf16 with A = weight fragment (M = o), B = sample fragment (N = pixel).
// LDS: S[64 rows(pixel)][128B] at 0 (8KB, XOR-swizzled), W[256 rows(o)][128B] at 8192 (32KB,
// swizzle baked into global layout so global_load_lds stays linear).
__global__ __launch_bounds__(256, 2) void dsconv_main(const float* __restrict__ x,
                                                      const float* __restrict__ bias,
                                                      const unsigned short* __restrict__ wt_sw,
                                                      const float* __restrict__ sxw,
                                                      const float* __restrict__ syw,
                                                      float* __restrict__ out) {
  __shared__ __align__(16) char smem[40960];
  int bid = blockIdx.x;
  int m = (bid & 7) * 288 + (bid >> 3);          // XCD swizzle, 2304 % 8 == 0 (bijective)
  int b = m / 576; int rm = m - b * 576;
  int y = rm / 3; int x0 = (rm - y * 3) * 64;
  int tid = threadIdx.x;
  int wu = __builtin_amdgcn_readfirstlane(tid >> 6);  // wave id, provably uniform
  int l = tid & 63;
  int px = x0 + l;
  float fpx = (float)px, fpy = (float)y;
  float sxv = sxw[b * HW + y * WW + px];
  float syv = syw[b * HW + y * WW + px];
  int col = l & 15, g = l >> 4;
  int swzw = (l & 7) << 4;        // ds_write swizzle (row = lane = pixel)
  int swzr = (col & 7) << 4;      // frag-read swizzle (row&7 == col&7 for all frags)
  int wt_lane = ((wu * 8 + (l >> 3)) * 512) + ((l & 7) * 16);  // per-lane W-stage byte offset
  const char* wt_base = (const char*)wt_sw;

  f32x4 acc[4][4];
#pragma unroll
  for (int i = 0; i < 4; ++i)
#pragma unroll
    for (int j = 0; j < 4; ++j)
      acc[i][j] = (f32x4){0.f, 0.f, 0.f, 0.f};

#pragma unroll 1
  for (int t = 0; t < 9; ++t) {
    float cx = (float)(t % 3 - 1), cy = (float)(t / 3 - 1);
    float gx = fminf(fmaxf(fpx + cx * sxv, 0.f), 191.f);
    float gy = fminf(fmaxf(fpy + cy * syv, 0.f), 191.f);
    int ix0 = (int)gx, iy0 = (int)gy;
    float fx = gx - (float)ix0, fy = gy - (float)iy0;
    int ix1 = min(ix0 + 1, 191), iy1 = min(iy0 + 1, 191);
    float w00 = (1.f - fx) * (1.f - fy), w01 = fx * (1.f - fy);
    float w10 = (1.f - fx) * fy,        w11 = fx * fy;
    int o00 = iy0 * WW + ix0, o01 = iy0 * WW + ix1;
    int o10 = iy1 * WW + ix0, o11 = iy1 * WW + ix1;
#pragma unroll 1
    for (int cb = 0; cb < 4; ++cb) {
      __syncthreads();   // previous MFMA done reading LDS
      // ---- S-gen: lane = pixel, wave w covers c-local [w*16, w*16+16) ----
#pragma unroll
      for (int j = 0; j < 2; ++j) {
        bh8 vp;
#pragma unroll
        for (int jj = 0; jj < 8; ++jj) {
          const float* pl = x + (size_t)(b * CC + cb * 64 + wu * 16 + j * 8 + jj) * HW;
          float s = w00 * pl[o00] + w01 * pl[o01] + w10 * pl[o10] + w11 * pl[o11];
          vp[jj] = (short)f2bf(s);
        }
        *(bh8*)(smem + l * 128 + (((wu * 16 + j * 8) * 2) ^ swzw)) = vp;
      }
      // ---- W-stage: 32KB via global_load_lds dwordx4, linear LDS dest ----
      const char* src0 = wt_base + t * 131072 + cb * 128 + wt_lane;
#pragma unroll
      for (int i = 0; i < 8; ++i) {
        __builtin_amdgcn_global_load_lds(
            (const __attribute__((address_space(1))) unsigned int*)(src0 + i * 16384),
            (__attribute__((address_space(3))) unsigned int*)(smem + 8192 + i * 4096 + wu * 1024),
            16, 0, 0);
      }
      __syncthreads();   // compiler drains vmcnt/lgkmcnt before s_barrier
      // ---- MFMA: BK=64 = 2 k-steps of 32 ----
#pragma unroll
      for (int kk = 0; kk < 2; ++kk) {
        bh8 wf[4], sf[4];
        int uo = (kk * 64 + g * 16) ^ swzr;
#pragma unroll
        for (int f = 0; f < 4; ++f) {
          wf[f] = *(const bh8*)(smem + 8192 + (wu * 64 + f * 16 + col) * 128 + uo);
          sf[f] = *(const bh8*)(smem + (f * 16 + col) * 128 + uo);
        }
#pragma unroll
        for (int fm = 0; fm < 4; ++fm)
#pragma unroll
          for (int fn = 0; fn < 4; ++fn)
            acc[fm][fn] = __builtin_amdgcn_mfma_f32_16x16x32_bf16(wf[fm], sf[fn], acc[fm][fn], 0, 0, 0);
      }
    }
  }
  // ---- epilogue: D row = o (M), col = pixel (N) -> 16 consecutive x per store group ----
#pragma unroll
  for (int fm = 0; fm < 4; ++fm)
#pragma unroll
    for (int r = 0; r < 4; ++r) {
      int o = wu * 64 + fm * 16 + g * 4 + r;
      float bv = bias[o];
      size_t ob = ((size_t)(b * OO + o) * HH + y) * WW + x0;
#pragma unroll
      for (int fn = 0; fn < 4; ++fn)
        out[ob + fn * 16 + col] = acc[fm][fn][r] + bv;
    }
}

extern "C" void kernel_launch(void* const* d_in, const int* in_sizes, int n_in,
                              void* d_out, int out_size, void* d_ws, size_t ws_size,
                              hipStream_t stream) {
  (void)in_sizes; (void)n_in; (void)out_size; (void)ws_size;
  const float* x      = (const float*)d_in[0];
  const float* weight = (const float*)d_in[1];
  const float* bias   = (const float*)d_in[2];
  const float* sp_w   = (const float*)d_in[3];
  const float* sp_b   = (const float*)d_in[4];
  float* out = (float*)d_out;
  char* ws = (char*)d_ws;
  // ws layout: sx [0, 589824), sy [589824, 1179648), wt_sw [1179648, 2359296)
  float* sxw = (float*)ws;
  float* syw = (float*)(ws + 589824);
  unsigned short* wt = (unsigned short*)(ws + 1179648);

  wt_transform<<<256, 256, 0, stream>>>(weight, wt);
  scale_pred<<<576, 256, 0, stream>>>(x, sp_w, sp_b, sxw, syw);
  dsconv_main<<<2304, 256, 0, stream>>>(x, bias, wt, sxw, syw, out);
}